// Round 1
// baseline (2907.087 us; speedup 1.0000x reference)
//
#include <hip/hip_runtime.h>

// Problem constants
#define BB 4
#define SS 4096
#define DD 2048
#define NHEAD 16
#define HDIM 128
#define MM (BB * SS)   // 16384 rows

typedef _Float16 f16;
typedef __attribute__((ext_vector_type(8))) _Float16 half8;
typedef __attribute__((ext_vector_type(4))) _Float16 half4;
typedef __attribute__((ext_vector_type(4))) float floatx4;

typedef __attribute__((address_space(3))) char lds_char;
typedef const __attribute__((address_space(1))) char glb_char;

__device__ __forceinline__ void async_copy16(const void* g, void* l) {
    // global -> LDS direct copy, 16B per lane; LDS dest = wave-uniform base + lane*16
    __builtin_amdgcn_global_load_lds((glb_char*)g, (lds_char*)l, 16, 0, 0);
}

// ---------------- cast fp32 -> fp16 (vectorized) ----------------
__global__ __launch_bounds__(256) void cast_f32_f16_kernel(
    const float* __restrict__ src, f16* __restrict__ dst, int n4) {
    int i = blockIdx.x * blockDim.x + threadIdx.x;
    if (i < n4) {
        float4 v = ((const float4*)src)[i];
        half4 h;
        h[0] = (f16)v.x; h[1] = (f16)v.y; h[2] = (f16)v.z; h[3] = (f16)v.w;
        ((half4*)dst)[i] = h;
    }
}

// ---------------- transpose + cast: dst[e][d] = src[d][e] ----------------
__global__ __launch_bounds__(256) void transpose_cast_kernel(
    const float* __restrict__ src, f16* __restrict__ dst, int dim) {
    __shared__ float tile[32][33];   // +1 pad: conflict-free transpose
    int tx = threadIdx.x & 31, ty = threadIdx.x >> 5;  // 32 x 8
    int bx = blockIdx.x * 32, by = blockIdx.y * 32;
#pragma unroll
    for (int r = 0; r < 4; ++r)
        tile[ty + 8 * r][tx] = src[(size_t)(by + ty + 8 * r) * dim + bx + tx];
    __syncthreads();
#pragma unroll
    for (int r = 0; r < 4; ++r)
        dst[(size_t)(bx + ty + 8 * r) * dim + by + tx] = (f16)tile[tx][ty + 8 * r];
}

// ---------------- fp16 MFMA GEMM: C[M,N] = A[M,K] @ Bt[N,K]^T ----------------
// 128x128 tile, BK=32, 256 threads = 4 waves in 2x2, each wave 64x64 (4x4 frags of 16x16x32)
// MODE 0: out fp16 with fp32 bias (input projection -> x buffer)
// MODE 1: out fp32, no bias (output projection -> d_out)
template <int MODE>
__global__ __launch_bounds__(256) void gemm_f16_kernel(
    const f16* __restrict__ A, const f16* __restrict__ Bt,
    const float* __restrict__ bias, f16* __restrict__ outH,
    float* __restrict__ outF, int M, int N, int K) {
    __shared__ __align__(16) char smem[16384];   // As 8KB | Bs 8KB
    f16* As = (f16*)smem;
    f16* Bs = (f16*)(smem + 8192);

    const int tid = threadIdx.x;
    const int lane = tid & 63;
    const int wave = tid >> 6;
    const int wm = wave >> 1, wn = wave & 1;
    const int lm = lane & 15, quad = lane >> 4;
    const int m0 = blockIdx.y * 128, n0 = blockIdx.x * 128;

    floatx4 acc[4][4];
#pragma unroll
    for (int i = 0; i < 4; ++i)
#pragma unroll
        for (int j = 0; j < 4; ++j)
#pragma unroll
            for (int r = 0; r < 4; ++r) acc[i][j][r] = 0.f;

    // staging map: thread t loads 16B: row = t>>2 (+64 for round 1), k-elem = (t&3)*8
    const int srow = tid >> 2;
    const int skk = (tid & 3) * 8;
    const int wbase = (tid >> 6) * 1024;  // wave-uniform LDS byte base
    const f16* Ag = A + (size_t)(m0 + srow) * K + skk;
    const f16* Bg = Bt + (size_t)(n0 + srow) * K + skk;

    for (int kb = 0; kb < K; kb += 32) {
        async_copy16(Ag + kb, smem + 0 + wbase);
        async_copy16(Ag + (size_t)64 * K + kb, smem + 4096 + wbase);
        async_copy16(Bg + kb, smem + 8192 + wbase);
        async_copy16(Bg + (size_t)64 * K + kb, smem + 12288 + wbase);
        asm volatile("s_waitcnt vmcnt(0)" ::: "memory");
        __syncthreads();

        half8 af[4], bf[4];
#pragma unroll
        for (int i = 0; i < 4; ++i)
            af[i] = *(const half8*)(As + (wm * 64 + i * 16 + lm) * 32 + quad * 8);
#pragma unroll
        for (int j = 0; j < 4; ++j)
            bf[j] = *(const half8*)(Bs + (wn * 64 + j * 16 + lm) * 32 + quad * 8);
#pragma unroll
        for (int i = 0; i < 4; ++i)
#pragma unroll
            for (int j = 0; j < 4; ++j)
                acc[i][j] = __builtin_amdgcn_mfma_f32_16x16x32_f16(af[i], bf[j], acc[i][j], 0, 0, 0);
        __syncthreads();
    }

    // epilogue: C/D layout col = lane&15, row = quad*4 + r
#pragma unroll
    for (int j = 0; j < 4; ++j) {
        int col = n0 + wn * 64 + j * 16 + lm;
        float bj = (MODE == 0) ? bias[col] : 0.f;
#pragma unroll
        for (int i = 0; i < 4; ++i) {
            int row0 = m0 + wm * 64 + i * 16 + quad * 4;
#pragma unroll
            for (int r = 0; r < 4; ++r) {
                float v = acc[i][j][r] + bj;
                if (MODE == 0) outH[(size_t)(row0 + r) * N + col] = (f16)v;
                else           outF[(size_t)(row0 + r) * N + col] = v;
            }
        }
    }
}

// ---------------- sequential scan: one workgroup per (b, n) ----------------
// state h (128, fp32) ; W_n (128x128 fp32) held in VGPRs across the block:
// thread (kq = tid&31, p = tid>>5): owns W[p*16 .. p*16+15][kq*4 .. kq*4+3]
__global__ __launch_bounds__(256) void scan_kernel(
    const f16* __restrict__ xb, const float* __restrict__ state_weight,
    const float* __restrict__ input_state, f16* __restrict__ yb) {
    const int b = blockIdx.x >> 4;
    const int n = blockIdx.x & 15;
    const int tid = threadIdx.x;
    const int kq = tid & 31, p = tid >> 5;
    const int k0 = kq * 4;

    __shared__ float hs[128];
    __shared__ float ps[8][132];   // partial sums, padded stride

    // load this head's weights into registers (64 floats / thread)
    float4 wreg[16];
    const float* Wn = state_weight + (size_t)n * HDIM * HDIM;
#pragma unroll
    for (int hh = 0; hh < 16; ++hh)
        wreg[hh] = *(const float4*)&Wn[(size_t)(p * 16 + hh) * HDIM + k0];

    if (tid < 128) hs[tid] = input_state[((size_t)b * NHEAD + n) * HDIM + tid];
    __syncthreads();

    const f16* xrow = xb + (size_t)b * SS * DD + n * HDIM;
    f16* yrow = yb + (size_t)b * SS * DD + n * HDIM;

    float xv = (tid < 128) ? (float)xrow[tid] : 0.f;

    for (int t = 0; t < SS; ++t) {
        // Phase A: all 256 threads compute partial dot products (fp32, W in regs)
        float a0 = 0.f, a1 = 0.f, a2 = 0.f, a3 = 0.f;
#pragma unroll
        for (int q = 0; q < 4; ++q) {
            float4 h4 = *(const float4*)&hs[p * 16 + q * 4];
            float4 w0 = wreg[q * 4 + 0], w1 = wreg[q * 4 + 1];
            float4 w2 = wreg[q * 4 + 2], w3 = wreg[q * 4 + 3];
            a0 += h4.x * w0.x; a1 += h4.x * w0.y; a2 += h4.x * w0.z; a3 += h4.x * w0.w;
            a0 += h4.y * w1.x; a1 += h4.y * w1.y; a2 += h4.y * w1.z; a3 += h4.y * w1.w;
            a0 += h4.z * w2.x; a1 += h4.z * w2.y; a2 += h4.z * w2.z; a3 += h4.z * w2.w;
            a0 += h4.w * w3.x; a1 += h4.w * w3.y; a2 += h4.w * w3.z; a3 += h4.w * w3.w;
        }
        float4 pv; pv.x = a0; pv.y = a1; pv.z = a2; pv.w = a3;
        *(float4*)&ps[p][k0] = pv;

        // prefetch next x while partials settle
        float xv_next = 0.f;
        if (tid < 128 && t + 1 < SS) xv_next = (float)xrow[(size_t)(t + 1) * DD + tid];
        __syncthreads();

        // Phase B: 128 threads reduce, add x, tanh, write state + y
        if (tid < 128) {
            float v = xv;
#pragma unroll
            for (int pp = 0; pp < 8; ++pp) v += ps[pp][tid];
            float ex = __expf(2.f * v);
            float ns = 1.f - 2.f * __builtin_amdgcn_rcpf(ex + 1.f);
            hs[tid] = ns;
            yrow[(size_t)t * DD + tid] = (f16)ns;
        }
        __syncthreads();
        xv = xv_next;
    }
}

// ---------------- launch ----------------
extern "C" void kernel_launch(void* const* d_in, const int* in_sizes, int n_in,
                              void* d_out, int out_size, void* d_ws, size_t ws_size,
                              hipStream_t stream) {
    const float* input       = (const float*)d_in[0];
    const float* input_state = (const float*)d_in[1];
    const float* w_in        = (const float*)d_in[2];
    const float* b_in        = (const float*)d_in[3];
    const float* state_w     = (const float*)d_in[4];
    const float* w_out       = (const float*)d_in[5];
    float* out = (float*)d_out;

    // workspace layout (144 MB total):
    //   [0, 64MB)      Ab  : input cast to f16   (reused as yb after GEMM1)
    //   [64, 72MB)     W1b : w_in^T  f16
    //   [72, 80MB)     W2b : w_out^T f16
    //   [80, 144MB)    xb  : projected input, f16
    char* ws = (char*)d_ws;
    f16* Ab  = (f16*)ws;
    f16* W1b = (f16*)(ws + 67108864);
    f16* W2b = (f16*)(ws + 75497472);
    f16* xb  = (f16*)(ws + 83886080);
    f16* yb  = Ab;  // alias: Ab is dead after GEMM1

    cast_f32_f16_kernel<<<(MM * DD / 4 + 255) / 256, 256, 0, stream>>>(input, Ab, MM * DD / 4);

    dim3 tg(DD / 32, DD / 32);
    transpose_cast_kernel<<<tg, 256, 0, stream>>>(w_in, W1b, DD);
    transpose_cast_kernel<<<tg, 256, 0, stream>>>(w_out, W2b, DD);

    dim3 gg(DD / 128, MM / 128);
    gemm_f16_kernel<0><<<gg, 256, 0, stream>>>(Ab, W1b, b_in, xb, nullptr, MM, DD, DD);

    scan_kernel<<<BB * NHEAD, 256, 0, stream>>>(xb, state_w, input_state, yb);

    gemm_f16_kernel<1><<<gg, 256, 0, stream>>>(yb, W2b, nullptr, nullptr, out, MM, DD, DD);
}